// Round 1
// baseline (607.219 us; speedup 1.0000x reference)
//
#include <hip/hip_runtime.h>
#include <hip/hip_bf16.h>
#include <cstdint>
#include <cstddef>

#define B_ 2
#define S_ 2048
#define D_ 2048
#define H_ 16
#define HD_ 128

typedef __bf16 bf16_t;
typedef __bf16 bf16x8 __attribute__((ext_vector_type(8)));
typedef __bf16 bf16x4 __attribute__((ext_vector_type(4)));
typedef float f32x4 __attribute__((ext_vector_type(4)));

// async global->LDS, 16B per lane. LDS dest is wave-uniform base + lane*16.
__device__ __forceinline__ void async16(const bf16_t* g, bf16_t* l) {
    __builtin_amdgcn_global_load_lds(
        (const __attribute__((address_space(1))) unsigned int*)g,
        (__attribute__((address_space(3))) unsigned int*)l, 16, 0, 0);
}

// ---------------- fp32 -> bf16 convert ----------------
__global__ void f2b_kernel(const float* __restrict__ in, bf16_t* __restrict__ out, int n) {
    int i = (blockIdx.x * blockDim.x + threadIdx.x) * 4;
    if (i >= n) return;
    float4 v = *(const float4*)(in + i);
    bf16x4 o = { (bf16_t)v.x, (bf16_t)v.y, (bf16_t)v.z, (bf16_t)v.w };
    *(bf16x4*)(out + i) = o;
}

// ---------------- RoPE (in-place on q or k, bf16) ----------------
// grid.y: 0 -> q, 1 -> k. One thread per (row, head, pair i<64).
__global__ void rope_kernel(bf16_t* __restrict__ q, bf16_t* __restrict__ k) {
    int idx = blockIdx.x * blockDim.x + threadIdx.x;  // [0, B*S*H*64)
    bf16_t* p = (blockIdx.y == 0) ? q : k;
    int i = idx & 63;
    int rest = idx >> 6;
    int h = rest & (H_ - 1);
    int row = rest >> 4;          // [0, B*S)
    int s = row & (S_ - 1);
    // inv_freq[i] = 10000^(-i/64); ang = s * inv_freq
    float inv = expf(-(float)i * 0.14391156831212787f);
    float ang = (float)s * inv;
    float c = cosf(ang), sn = sinf(ang);
    size_t base = (size_t)row * D_ + (size_t)h * HD_ + i;
    float x0 = (float)p[base];
    float x1 = (float)p[base + 64];
    p[base]      = (bf16_t)(x0 * c - x1 * sn);
    p[base + 64] = (bf16_t)(x1 * c + x0 * sn);
}

// ---------------- GEMM: C[M,N] = A[M,K] * Bt[N,K]^T  (m97 structure) ----------------
// 256 threads = 4 waves, each wave computes 64x64; tile 128x128, BK=32.
template <bool F32OUT>
__global__ __launch_bounds__(256) void gemm_bt(const bf16_t* __restrict__ A,
                                               const bf16_t* __restrict__ Bt,
                                               void* __restrict__ Cout,
                                               int M, int N, int K) {
    __shared__ __align__(16) bf16_t As[128 * 32];
    __shared__ __align__(16) bf16_t Bs[128 * 32];
    int t = threadIdx.x;
    int w = t >> 6, lane = t & 63, lo = lane & 15, hi = lane >> 4;
    int m0 = blockIdx.y * 128, n0 = blockIdx.x * 128;
    int wm = (w & 1) * 64, wn = (w >> 1) * 64;
    f32x4 acc[4][4] = {};
    const bf16_t* ga = A + (size_t)(m0 + (t >> 2)) * K + (t & 3) * 8;
    const bf16_t* gb = Bt + (size_t)(n0 + (t >> 2)) * K + (t & 3) * 8;
    for (int k0 = 0; k0 < K; k0 += 32) {
        async16(ga + k0,            As + t * 8);
        async16(ga + (size_t)64 * K + k0, As + 2048 + t * 8);
        async16(gb + k0,            Bs + t * 8);
        async16(gb + (size_t)64 * K + k0, Bs + 2048 + t * 8);
        __syncthreads();
        bf16x8 af[4], bfr[4];
#pragma unroll
        for (int ms = 0; ms < 4; ++ms)
            af[ms] = *(const bf16x8*)(As + (wm + ms * 16 + lo) * 32 + hi * 8);
#pragma unroll
        for (int ns = 0; ns < 4; ++ns)
            bfr[ns] = *(const bf16x8*)(Bs + (wn + ns * 16 + lo) * 32 + hi * 8);
#pragma unroll
        for (int ms = 0; ms < 4; ++ms)
#pragma unroll
            for (int ns = 0; ns < 4; ++ns)
                acc[ms][ns] = __builtin_amdgcn_mfma_f32_16x16x32_bf16(af[ms], bfr[ns], acc[ms][ns], 0, 0, 0);
        __syncthreads();
    }
    // epilogue: C row = m0+wm+ms*16+hi*4+r, col = n0+wn+ns*16+lo
    if (F32OUT) {
        float* C = (float*)Cout;
#pragma unroll
        for (int ms = 0; ms < 4; ++ms)
#pragma unroll
            for (int ns = 0; ns < 4; ++ns)
#pragma unroll
                for (int r = 0; r < 4; ++r)
                    C[(size_t)(m0 + wm + ms * 16 + hi * 4 + r) * N + n0 + wn + ns * 16 + lo] = acc[ms][ns][r];
    } else {
        bf16_t* C = (bf16_t*)Cout;
#pragma unroll
        for (int ms = 0; ms < 4; ++ms)
#pragma unroll
            for (int ns = 0; ns < 4; ++ns)
#pragma unroll
                for (int r = 0; r < 4; ++r)
                    C[(size_t)(m0 + wm + ms * 16 + hi * 4 + r) * N + n0 + wn + ns * 16 + lo] = (bf16_t)acc[ms][ns][r];
    }
}

// ---------------- Flash attention (causal, online softmax) ----------------
// grid: (S/64, B*H). 256 threads = 4 waves; wave w owns q rows [q0+w*16, q0+w*16+16).
#define BQ 64
#define BK 64
#define QKS 136   // row stride for Qs/Ks: 272B = 17*16, 2-way bank alias only
#define VTS 72    // row stride for Vt/Ps: 144B = 9*16
__global__ __launch_bounds__(256) void attn_kernel(const bf16_t* __restrict__ q,
                                                   const bf16_t* __restrict__ k,
                                                   const bf16_t* __restrict__ v,
                                                   bf16_t* __restrict__ o) {
    __shared__ __align__(16) bf16_t Qs[BQ * QKS];
    __shared__ __align__(16) bf16_t Ks[BK * QKS];
    __shared__ __align__(16) bf16_t Vt[HD_ * VTS];        // Vt[d][kk] = V[kk][d]
    __shared__ __align__(16) bf16_t Ps[4 * 16 * VTS];     // per-wave P, A-operand layout
    int t = threadIdx.x;
    int w = t >> 6, lane = t & 63, lo = lane & 15, hi = lane >> 4;
    int q0 = blockIdx.x * BQ;
    int b = blockIdx.y >> 4, h = blockIdx.y & 15;
    const size_t head_off = (size_t)b * S_ * D_ + (size_t)h * HD_;

    // stage Q tile (64 x 128)
#pragma unroll
    for (int it = 0; it < 4; ++it) {
        int c = t + it * 256;
        int r = c >> 4, d0 = (c & 15) * 8;
        *(bf16x8*)(Qs + r * QKS + d0) =
            *(const bf16x8*)(q + head_off + (size_t)(q0 + r) * D_ + d0);
    }

    float m_r[4] = {-1e30f, -1e30f, -1e30f, -1e30f};
    float l_r[4] = {0.f, 0.f, 0.f, 0.f};
    f32x4 oacc[8] = {};
    const float scale = 0.08838834764831845f;  // 1/sqrt(128)

    int nkt = blockIdx.x + 1;
    for (int kt = 0; kt < nkt; ++kt) {
        int k0 = kt * BK;
        __syncthreads();  // prior-iter reads done (also publishes Q on iter 0)
        // stage K (rows) and V (transposed)
#pragma unroll
        for (int it = 0; it < 4; ++it) {
            int c = t + it * 256;
            int r = c >> 4, d0 = (c & 15) * 8;
            *(bf16x8*)(Ks + r * QKS + d0) =
                *(const bf16x8*)(k + head_off + (size_t)(k0 + r) * D_ + d0);
            bf16x8 vv = *(const bf16x8*)(v + head_off + (size_t)(k0 + r) * D_ + d0);
            int p = c & 15;
#pragma unroll
            for (int jj = 0; jj < 8; ++jj) {
                int j = (jj + p) & 7;  // rotate to spread LDS banks
                Vt[(d0 + j) * VTS + r] = vv[j];
            }
        }
        __syncthreads();

        // scores: S[q, kcol] for q rows w*16+lo.., 64 k cols
        f32x4 sacc[4] = {};
#pragma unroll
        for (int c = 0; c < 4; ++c) {
            bf16x8 aq = *(const bf16x8*)(Qs + (w * 16 + lo) * QKS + c * 32 + hi * 8);
#pragma unroll
            for (int nt = 0; nt < 4; ++nt) {
                bf16x8 bk = *(const bf16x8*)(Ks + (nt * 16 + lo) * QKS + c * 32 + hi * 8);
                sacc[nt] = __builtin_amdgcn_mfma_f32_16x16x32_bf16(aq, bk, sacc[nt], 0, 0, 0);
            }
        }
        float sc[4][4];
#pragma unroll
        for (int nt = 0; nt < 4; ++nt)
#pragma unroll
            for (int r = 0; r < 4; ++r) sc[nt][r] = sacc[nt][r] * scale;
        if (k0 == q0) {  // only the diagonal tile needs the causal mask
#pragma unroll
            for (int nt = 0; nt < 4; ++nt) {
                int kg = k0 + nt * 16 + lo;
#pragma unroll
                for (int r = 0; r < 4; ++r) {
                    int qg = q0 + w * 16 + hi * 4 + r;
                    if (kg > qg) sc[nt][r] = -1e30f;
                }
            }
        }
        // online softmax per row (rows live in hi-groups; reduce over lo via xor 1..8)
#pragma unroll
        for (int r = 0; r < 4; ++r) {
            float mx = fmaxf(fmaxf(sc[0][r], sc[1][r]), fmaxf(sc[2][r], sc[3][r]));
            mx = fmaxf(mx, __shfl_xor(mx, 1));
            mx = fmaxf(mx, __shfl_xor(mx, 2));
            mx = fmaxf(mx, __shfl_xor(mx, 4));
            mx = fmaxf(mx, __shfl_xor(mx, 8));
            float nm = fmaxf(m_r[r], mx);
            float alpha = __expf(m_r[r] - nm);
            m_r[r] = nm;
            float rs = 0.f;
#pragma unroll
            for (int nt = 0; nt < 4; ++nt) {
                float e = __expf(sc[nt][r] - nm);
                sc[nt][r] = e;
                rs += e;
            }
            rs += __shfl_xor(rs, 1);
            rs += __shfl_xor(rs, 2);
            rs += __shfl_xor(rs, 4);
            rs += __shfl_xor(rs, 8);
            l_r[r] = l_r[r] * alpha + rs;
#pragma unroll
            for (int dt = 0; dt < 8; ++dt) oacc[dt][r] *= alpha;
        }
        // P: C-layout -> LDS -> A-operand layout (wave-local, DS ops in-order per wave)
        bf16_t* myPs = Ps + w * 16 * VTS;
#pragma unroll
        for (int nt = 0; nt < 4; ++nt)
#pragma unroll
            for (int r = 0; r < 4; ++r)
                myPs[(hi * 4 + r) * VTS + nt * 16 + lo] = (bf16_t)sc[nt][r];
        // PV: O[q, d] += P[q, kk] * V[kk, d]
#pragma unroll
        for (int c = 0; c < 2; ++c) {
            bf16x8 ap = *(const bf16x8*)(myPs + lo * VTS + c * 32 + hi * 8);
#pragma unroll
            for (int dt = 0; dt < 8; ++dt) {
                bf16x8 bv = *(const bf16x8*)(Vt + (dt * 16 + lo) * VTS + c * 32 + hi * 8);
                oacc[dt] = __builtin_amdgcn_mfma_f32_16x16x32_bf16(ap, bv, oacc[dt], 0, 0, 0);
            }
        }
    }
    // epilogue: O / l
#pragma unroll
    for (int r = 0; r < 4; ++r) {
        float rl = 1.0f / l_r[r];
        size_t row = (size_t)(q0 + w * 16 + hi * 4 + r);
#pragma unroll
        for (int dt = 0; dt < 8; ++dt)
            o[head_off + row * D_ + dt * 16 + lo] = (bf16_t)(oacc[dt][r] * rl);
    }
}

// ---------------- launch ----------------
extern "C" void kernel_launch(void* const* d_in, const int* in_sizes, int n_in,
                              void* d_out, int out_size, void* d_ws, size_t ws_size,
                              hipStream_t stream) {
    (void)in_sizes; (void)n_in; (void)out_size; (void)ws_size;
    const float* x  = (const float*)d_in[0];
    const float* Wq = (const float*)d_in[1];
    const float* Wk = (const float*)d_in[2];
    const float* Wv = (const float*)d_in[3];
    const float* Wo = (const float*)d_in[4];
    char* ws = (char*)d_ws;
    bf16_t* xb  = (bf16_t*)(ws);                 // 16 MB
    bf16_t* Wqb = (bf16_t*)(ws + 16777216);      // 8 MB
    bf16_t* Wkb = (bf16_t*)(ws + 25165824);
    bf16_t* Wvb = (bf16_t*)(ws + 33554432);
    bf16_t* Wob = (bf16_t*)(ws + 41943040);
    bf16_t* qb  = (bf16_t*)(ws + 50331648);      // 16 MB each
    bf16_t* kb  = (bf16_t*)(ws + 67108864);
    bf16_t* vb  = (bf16_t*)(ws + 83886080);
    bf16_t* ob  = (bf16_t*)(ws + 100663296);
    float* out = (float*)d_out;

    const int nx = B_ * S_ * D_;   // 8388608
    const int nw = D_ * D_;        // 4194304
    f2b_kernel<<<nx / 1024, 256, 0, stream>>>(x, xb, nx);
    f2b_kernel<<<nw / 1024, 256, 0, stream>>>(Wq, Wqb, nw);
    f2b_kernel<<<nw / 1024, 256, 0, stream>>>(Wk, Wkb, nw);
    f2b_kernel<<<nw / 1024, 256, 0, stream>>>(Wv, Wvb, nw);
    f2b_kernel<<<nw / 1024, 256, 0, stream>>>(Wo, Wob, nw);

    dim3 gg(D_ / 128, (B_ * S_) / 128);  // (16, 32)
    gemm_bt<false><<<gg, 256, 0, stream>>>(xb, Wqb, qb, B_ * S_, D_, D_);
    gemm_bt<false><<<gg, 256, 0, stream>>>(xb, Wkb, kb, B_ * S_, D_, D_);
    gemm_bt<false><<<gg, 256, 0, stream>>>(xb, Wvb, vb, B_ * S_, D_, D_);

    rope_kernel<<<dim3((B_ * S_ * H_ * 64) / 256, 2), 256, 0, stream>>>(qb, kb);

    attn_kernel<<<dim3(S_ / BQ, B_ * H_), 256, 0, stream>>>(qb, kb, vb, ob);

    gemm_bt<true><<<gg, 256, 0, stream>>>(ob, Wob, out, B_ * S_, D_, D_);
}

// Round 2
// 531.784 us; speedup vs baseline: 1.1419x; 1.1419x over previous
//
#include <hip/hip_runtime.h>
#include <hip/hip_bf16.h>
#include <cstdint>
#include <cstddef>

#define B_ 2
#define S_ 2048
#define D_ 2048
#define H_ 16
#define HD_ 128

typedef __bf16 bf16_t;
typedef __bf16 bf16x8 __attribute__((ext_vector_type(8)));
typedef __bf16 bf16x4 __attribute__((ext_vector_type(4)));
typedef float f32x4 __attribute__((ext_vector_type(4)));

// async global->LDS, 16B per lane. LDS dest must be wave-uniform base + lane*16.
__device__ __forceinline__ void async16(const bf16_t* g, bf16_t* l) {
    __builtin_amdgcn_global_load_lds(
        (const __attribute__((address_space(1))) unsigned int*)g,
        (__attribute__((address_space(3))) unsigned int*)l, 16, 0, 0);
}

// ---------------- fp32 -> bf16 convert ----------------
__global__ void f2b_kernel(const float* __restrict__ in, bf16_t* __restrict__ out, int n) {
    int i = (blockIdx.x * blockDim.x + threadIdx.x) * 4;
    if (i >= n) return;
    float4 v = *(const float4*)(in + i);
    bf16x4 o = { (bf16_t)v.x, (bf16_t)v.y, (bf16_t)v.z, (bf16_t)v.w };
    *(bf16x4*)(out + i) = o;
}

// ---------------- RoPE (in-place on q or k, bf16), x8 vectorized ----------------
__global__ void rope_kernel(bf16_t* __restrict__ q, bf16_t* __restrict__ k) {
    int idx = blockIdx.x * blockDim.x + threadIdx.x;  // [0, B*S*H*8)
    bf16_t* p = (blockIdx.y == 0) ? q : k;
    int i0 = (idx & 7) * 8;
    int rest = idx >> 3;
    int h = rest & (H_ - 1);
    int row = rest >> 4;          // [0, B*S)
    int s = row & (S_ - 1);
    size_t base = (size_t)row * D_ + (size_t)h * HD_ + i0;
    bf16x8 x0 = *(bf16x8*)(p + base);
    bf16x8 x1 = *(bf16x8*)(p + base + 64);
    bf16x8 o0, o1;
#pragma unroll
    for (int j = 0; j < 8; ++j) {
        float inv = __expf(-(float)(i0 + j) * 0.14391156831212787f);
        float ang = (float)s * inv;
        float sn, c;
        __sincosf(ang, &sn, &c);
        float a = (float)x0[j], bb = (float)x1[j];
        o0[j] = (bf16_t)(a * c - bb * sn);
        o1[j] = (bf16_t)(bb * c + a * sn);
    }
    *(bf16x8*)(p + base) = o0;
    *(bf16x8*)(p + base + 64) = o1;
}

// ---------------- V transpose: vb [B][S][D] -> vtb [B][D][S] ----------------
#define TS 65
__global__ void transpose_v(const bf16_t* __restrict__ in, bf16_t* __restrict__ out) {
    __shared__ bf16_t T[64 * TS];
    int t = threadIdx.x;
    int d0 = blockIdx.x * 64;        // col tile in D
    int y0 = blockIdx.y * 64;        // row tile in B*S (never crosses b boundary)
#pragma unroll
    for (int i = 0; i < 2; ++i) {
        int ci = t + i * 256;
        int r = ci >> 3, c = (ci & 7) * 8;
        bf16x8 v = *(const bf16x8*)(in + (size_t)(y0 + r) * D_ + d0 + c);
#pragma unroll
        for (int j = 0; j < 8; ++j) T[r * TS + c + j] = v[j];
    }
    __syncthreads();
    int b = y0 >> 11, s0 = y0 & (S_ - 1);
    size_t obase = (size_t)b * D_ * S_;
#pragma unroll
    for (int i = 0; i < 2; ++i) {
        int ci = t + i * 256;
        int rr = ci >> 3, cc = (ci & 7) * 8;
        bf16x8 v;
#pragma unroll
        for (int j = 0; j < 8; ++j) v[j] = T[(cc + j) * TS + rr];
        *(bf16x8*)(out + obase + (size_t)(d0 + rr) * S_ + s0 + cc) = v;
    }
}

// ---------------- GEMM: C[M,N] = A[M,K] * Bt[N,K]^T  (m97 structure) ----------------
template <bool F32OUT>
__global__ __launch_bounds__(256) void gemm_bt(const bf16_t* __restrict__ A,
                                               const bf16_t* __restrict__ Bt,
                                               void* __restrict__ Cout,
                                               int M, int N, int K) {
    __shared__ __align__(16) bf16_t As[128 * 32];
    __shared__ __align__(16) bf16_t Bs[128 * 32];
    int t = threadIdx.x;
    int w = t >> 6, lane = t & 63, lo = lane & 15, hi = lane >> 4;
    int m0 = blockIdx.y * 128, n0 = blockIdx.x * 128;
    int wm = (w & 1) * 64, wn = (w >> 1) * 64;
    f32x4 acc[4][4] = {};
    const bf16_t* ga = A + (size_t)(m0 + (t >> 2)) * K + (t & 3) * 8;
    const bf16_t* gb = Bt + (size_t)(n0 + (t >> 2)) * K + (t & 3) * 8;
    for (int k0 = 0; k0 < K; k0 += 32) {
        async16(ga + k0,            As + t * 8);
        async16(ga + (size_t)64 * K + k0, As + 2048 + t * 8);
        async16(gb + k0,            Bs + t * 8);
        async16(gb + (size_t)64 * K + k0, Bs + 2048 + t * 8);
        __syncthreads();
        bf16x8 af[4], bfr[4];
#pragma unroll
        for (int ms = 0; ms < 4; ++ms)
            af[ms] = *(const bf16x8*)(As + (wm + ms * 16 + lo) * 32 + hi * 8);
#pragma unroll
        for (int ns = 0; ns < 4; ++ns)
            bfr[ns] = *(const bf16x8*)(Bs + (wn + ns * 16 + lo) * 32 + hi * 8);
#pragma unroll
        for (int ms = 0; ms < 4; ++ms)
#pragma unroll
            for (int ns = 0; ns < 4; ++ns)
                acc[ms][ns] = __builtin_amdgcn_mfma_f32_16x16x32_bf16(af[ms], bfr[ns], acc[ms][ns], 0, 0, 0);
        __syncthreads();
    }
    if (F32OUT) {
        float* C = (float*)Cout;
#pragma unroll
        for (int ms = 0; ms < 4; ++ms)
#pragma unroll
            for (int ns = 0; ns < 4; ++ns)
#pragma unroll
                for (int r = 0; r < 4; ++r)
                    C[(size_t)(m0 + wm + ms * 16 + hi * 4 + r) * N + n0 + wn + ns * 16 + lo] = acc[ms][ns][r];
    } else {
        bf16_t* C = (bf16_t*)Cout;
#pragma unroll
        for (int ms = 0; ms < 4; ++ms)
#pragma unroll
            for (int ns = 0; ns < 4; ++ns)
#pragma unroll
                for (int r = 0; r < 4; ++r)
                    C[(size_t)(m0 + wm + ms * 16 + hi * 4 + r) * N + n0 + wn + ns * 16 + lo] = (bf16_t)acc[ms][ns][r];
    }
}

// ---------------- Flash attention (causal, online softmax) ----------------
// grid: (S/128, B*H), 512 threads = 8 waves; wave w owns q rows [q0+w*16, +16).
// LDS tiles are XOR-swizzled (chunk^row), no padding -> async16 staging works,
// reads are 2-way-max bank aliased (free).
__global__ __launch_bounds__(512, 4) void attn_kernel(const bf16_t* __restrict__ q,
                                                      const bf16_t* __restrict__ k,
                                                      const bf16_t* __restrict__ vt,
                                                      bf16_t* __restrict__ o) {
    __shared__ __align__(16) bf16_t Ks[64 * 128];   // [krow][d], swz mask row&15
    __shared__ __align__(16) bf16_t Vs[128 * 64];   // [d][kk],  swz mask d&7
    __shared__ __align__(16) bf16_t Ps[8 * 16 * 64];// per-wave P, swz mask q&7
    int t = threadIdx.x;
    int w = t >> 6, lane = t & 63, lo = lane & 15, hi = lane >> 4;
    int q0 = blockIdx.x * 128;
    int b = blockIdx.y >> 4, h = blockIdx.y & 15;
    const size_t head_off = (size_t)b * S_ * D_ + (size_t)h * HD_;
    const size_t vhead_off = ((size_t)b * D_ + (size_t)h * HD_) * S_;

    // Q fragments in registers (loaded once)
    bf16x8 aq[4];
#pragma unroll
    for (int c = 0; c < 4; ++c)
        aq[c] = *(const bf16x8*)(q + head_off + (size_t)(q0 + w * 16 + lo) * D_ + c * 32 + hi * 8);

    float m_r[4] = {-1e30f, -1e30f, -1e30f, -1e30f};
    float l_r[4] = {0.f, 0.f, 0.f, 0.f};
    f32x4 oacc[8] = {};
    const float scale = 0.08838834764831845f;  // 1/sqrt(128)
    bf16_t* PsW = Ps + w * 1024;

    int nkt = 2 * (blockIdx.x + 1);
    for (int kt = 0; kt < nkt; ++kt) {
        int k0 = kt * 64;
        __syncthreads();  // prior-iter LDS reads complete
        // stage K: 16 chunks of 1024B, wave w does chunks {2w, 2w+1}
#pragma unroll
        for (int i = 0; i < 2; ++i) {
            int chunk = w * 2 + i;
            int r = chunk * 4 + (lane >> 4);                 // k-row 0..63
            int lc = (lane & 15) ^ (r & 15);                 // logical chunk for phys slot
            async16(k + head_off + (size_t)(k0 + r) * D_ + lc * 8,
                    Ks + chunk * 512 + lane * 8);
        }
        // stage V (from pre-transposed vtb): 16 chunks of 8 d-rows
#pragma unroll
        for (int i = 0; i < 2; ++i) {
            int chunk = w * 2 + i;
            int d = chunk * 8 + (lane >> 3);                 // 0..127
            int lc = (lane & 7) ^ (d & 7);
            async16(vt + vhead_off + (size_t)d * S_ + k0 + lc * 8,
                    Vs + chunk * 512 + lane * 8);
        }
        __syncthreads();  // staging visible (barrier drains vmcnt)

        if (k0 <= q0 + w * 16 + 15) {  // wave-uniform: skip fully-masked tiles
            // scores: S[q, kcol], q rows w*16+lo.., 64 k cols
            f32x4 sacc[4] = {};
#pragma unroll
            for (int c = 0; c < 4; ++c) {
#pragma unroll
                for (int nt = 0; nt < 4; ++nt) {
                    int row = nt * 16 + lo;
                    int pc = (c * 4 + hi) ^ lo;
                    bf16x8 bk = *(const bf16x8*)(Ks + row * 128 + pc * 8);
                    sacc[nt] = __builtin_amdgcn_mfma_f32_16x16x32_bf16(aq[c], bk, sacc[nt], 0, 0, 0);
                }
            }
            float sc[4][4];
#pragma unroll
            for (int nt = 0; nt < 4; ++nt)
#pragma unroll
                for (int r = 0; r < 4; ++r) sc[nt][r] = sacc[nt][r] * scale;
            if (k0 + 63 > q0 + w * 16) {  // tile overlaps diagonal for this wave
#pragma unroll
                for (int nt = 0; nt < 4; ++nt) {
                    int kg = k0 + nt * 16 + lo;
#pragma unroll
                    for (int r = 0; r < 4; ++r) {
                        int qg = q0 + w * 16 + hi * 4 + r;
                        if (kg > qg) sc[nt][r] = -1e30f;
                    }
                }
            }
            // online softmax per row (reduce over lo via xor 1..8)
#pragma unroll
            for (int r = 0; r < 4; ++r) {
                float mx = fmaxf(fmaxf(sc[0][r], sc[1][r]), fmaxf(sc[2][r], sc[3][r]));
                mx = fmaxf(mx, __shfl_xor(mx, 1));
                mx = fmaxf(mx, __shfl_xor(mx, 2));
                mx = fmaxf(mx, __shfl_xor(mx, 4));
                mx = fmaxf(mx, __shfl_xor(mx, 8));
                float nm = fmaxf(m_r[r], mx);
                float alpha = __expf(m_r[r] - nm);
                m_r[r] = nm;
                float rs = 0.f;
#pragma unroll
                for (int nt = 0; nt < 4; ++nt) {
                    float e = __expf(sc[nt][r] - nm);
                    sc[nt][r] = e;
                    rs += e;
                }
                rs += __shfl_xor(rs, 1);
                rs += __shfl_xor(rs, 2);
                rs += __shfl_xor(rs, 4);
                rs += __shfl_xor(rs, 8);
                l_r[r] = l_r[r] * alpha + rs;
#pragma unroll
                for (int dt = 0; dt < 8; ++dt) oacc[dt][r] *= alpha;
            }
            // P: C-layout -> LDS (swizzled) -> A-operand layout (wave-local)
#pragma unroll
            for (int nt = 0; nt < 4; ++nt)
#pragma unroll
                for (int r = 0; r < 4; ++r) {
                    int qrow = hi * 4 + r;
                    int col = nt * 16 + lo;
                    int pcw = (col >> 3) ^ (qrow & 7);
                    PsW[qrow * 64 + pcw * 8 + (col & 7)] = (bf16_t)sc[nt][r];
                }
            // PV: O[q, d] += P[q, kk] * V[kk, d]
#pragma unroll
            for (int c = 0; c < 2; ++c) {
                int pcp = (c * 4 + hi) ^ (lo & 7);
                bf16x8 ap = *(const bf16x8*)(PsW + lo * 64 + pcp * 8);
#pragma unroll
                for (int dt = 0; dt < 8; ++dt) {
                    int d = dt * 16 + lo;
                    int pv = (c * 4 + hi) ^ (lo & 7);
                    bf16x8 bv = *(const bf16x8*)(Vs + d * 64 + pv * 8);
                    oacc[dt] = __builtin_amdgcn_mfma_f32_16x16x32_bf16(ap, bv, oacc[dt], 0, 0, 0);
                }
            }
        }
    }
    // epilogue: O / l
#pragma unroll
    for (int r = 0; r < 4; ++r) {
        float rl = 1.0f / l_r[r];
        size_t row = (size_t)(q0 + w * 16 + hi * 4 + r);
#pragma unroll
        for (int dt = 0; dt < 8; ++dt)
            o[head_off + row * D_ + dt * 16 + lo] = (bf16_t)(oacc[dt][r] * rl);
    }
}

// ---------------- launch ----------------
extern "C" void kernel_launch(void* const* d_in, const int* in_sizes, int n_in,
                              void* d_out, int out_size, void* d_ws, size_t ws_size,
                              hipStream_t stream) {
    (void)in_sizes; (void)n_in; (void)out_size; (void)ws_size;
    const float* x  = (const float*)d_in[0];
    const float* Wq = (const float*)d_in[1];
    const float* Wk = (const float*)d_in[2];
    const float* Wv = (const float*)d_in[3];
    const float* Wo = (const float*)d_in[4];
    char* ws = (char*)d_ws;
    bf16_t* xb  = (bf16_t*)(ws);                 // 16 MB (dead after V GEMM)
    bf16_t* Wqb = (bf16_t*)(ws + 16777216);      // 8 MB
    bf16_t* Wkb = (bf16_t*)(ws + 25165824);
    bf16_t* Wvb = (bf16_t*)(ws + 33554432);
    bf16_t* Wob = (bf16_t*)(ws + 41943040);
    bf16_t* qb  = (bf16_t*)(ws + 50331648);      // 16 MB each
    bf16_t* kb  = (bf16_t*)(ws + 67108864);
    bf16_t* vb  = (bf16_t*)(ws + 83886080);
    bf16_t* ob  = (bf16_t*)(ws + 100663296);
    bf16_t* vtb = (bf16_t*)(ws);                 // aliases xb (dead by then)
    float* out = (float*)d_out;

    const int nx = B_ * S_ * D_;   // 8388608
    const int nw = D_ * D_;        // 4194304
    f2b_kernel<<<nx / 1024, 256, 0, stream>>>(x, xb, nx);
    f2b_kernel<<<nw / 1024, 256, 0, stream>>>(Wq, Wqb, nw);
    f2b_kernel<<<nw / 1024, 256, 0, stream>>>(Wk, Wkb, nw);
    f2b_kernel<<<nw / 1024, 256, 0, stream>>>(Wv, Wvb, nw);
    f2b_kernel<<<nw / 1024, 256, 0, stream>>>(Wo, Wob, nw);

    dim3 gg(D_ / 128, (B_ * S_) / 128);  // (16, 32)
    gemm_bt<false><<<gg, 256, 0, stream>>>(xb, Wqb, qb, B_ * S_, D_, D_);
    gemm_bt<false><<<gg, 256, 0, stream>>>(xb, Wkb, kb, B_ * S_, D_, D_);
    gemm_bt<false><<<gg, 256, 0, stream>>>(xb, Wvb, vb, B_ * S_, D_, D_);

    transpose_v<<<dim3(D_ / 64, (B_ * S_) / 64), 256, 0, stream>>>(vb, vtb);
    rope_kernel<<<dim3((B_ * S_ * H_ * 8) / 256, 2), 256, 0, stream>>>(qb, kb);

    attn_kernel<<<dim3(S_ / 128, B_ * H_), 512, 0, stream>>>(qb, kb, vtb, ob);

    gemm_bt<true><<<gg, 256, 0, stream>>>(ob, Wob, out, B_ * S_, D_, D_);
}

// Round 3
// 407.929 us; speedup vs baseline: 1.4885x; 1.3036x over previous
//
#include <hip/hip_runtime.h>
#include <hip/hip_bf16.h>
#include <cstdint>
#include <cstddef>

#define B_ 2
#define S_ 2048
#define D_ 2048
#define H_ 16
#define HD_ 128

typedef __bf16 bf16_t;
typedef __bf16 bf16x8 __attribute__((ext_vector_type(8)));
typedef __bf16 bf16x4 __attribute__((ext_vector_type(4)));
typedef short s16x4 __attribute__((ext_vector_type(4)));
typedef float f32x4 __attribute__((ext_vector_type(4)));

__device__ __forceinline__ void async16(const bf16_t* g, bf16_t* l) {
    __builtin_amdgcn_global_load_lds(
        (const __attribute__((address_space(1))) unsigned int*)g,
        (__attribute__((address_space(3))) unsigned int*)l, 16, 0, 0);
}

// K=16 bf16 MFMA with builtin-name portability chain
__device__ __forceinline__ f32x4 mfma16x16x16_bf16(bf16x4 a, bf16x4 b, f32x4 c) {
#if __has_builtin(__builtin_amdgcn_mfma_f32_16x16x16_bf16)
    return __builtin_amdgcn_mfma_f32_16x16x16_bf16(a, b, c, 0, 0, 0);
#elif __has_builtin(__builtin_amdgcn_mfma_f32_16x16x16bf16_1k)
    return __builtin_amdgcn_mfma_f32_16x16x16bf16_1k(
        __builtin_bit_cast(s16x4, a), __builtin_bit_cast(s16x4, b), c, 0, 0, 0);
#else
    f32x4 d = c;
    asm("v_mfma_f32_16x16x16_bf16 %0, %1, %2, %0" : "+v"(d) : "v"(a), "v"(b));
    return d;
#endif
}

// ---------------- fused fp32 -> bf16 convert (6 segments of 4194304) ----------------
__global__ void f2b_multi(const float* __restrict__ x, const float* __restrict__ wq,
                          const float* __restrict__ wk, const float* __restrict__ wv,
                          const float* __restrict__ wo, bf16_t* __restrict__ xb,
                          bf16_t* __restrict__ wqb, bf16_t* __restrict__ wkb,
                          bf16_t* __restrict__ wvb, bf16_t* __restrict__ wob) {
    const float* in; bf16_t* out;
    switch (blockIdx.y) {
        case 0: in = x;            out = xb;            break;
        case 1: in = x + 4194304;  out = xb + 4194304;  break;
        case 2: in = wq;           out = wqb;           break;
        case 3: in = wk;           out = wkb;           break;
        case 4: in = wv;           out = wvb;           break;
        default: in = wo;          out = wob;           break;
    }
    int i = (blockIdx.x * blockDim.x + threadIdx.x) * 4;
    float4 v = *(const float4*)(in + i);
    bf16x4 o = { (bf16_t)v.x, (bf16_t)v.y, (bf16_t)v.z, (bf16_t)v.w };
    *(bf16x4*)(out + i) = o;
}

// ---------------- RoPE (in-place, x8 vectorized); q gets 1/sqrt(HD) folded in ----------------
__global__ void rope_kernel(bf16_t* __restrict__ q, bf16_t* __restrict__ k) {
    int idx = blockIdx.x * blockDim.x + threadIdx.x;  // [0, B*S*H*8)
    bf16_t* p = (blockIdx.y == 0) ? q : k;
    float sc = (blockIdx.y == 0) ? 0.08838834764831845f : 1.0f;
    int i0 = (idx & 7) * 8;
    int rest = idx >> 3;
    int h = rest & (H_ - 1);
    int row = rest >> 4;
    int s = row & (S_ - 1);
    size_t base = (size_t)row * D_ + (size_t)h * HD_ + i0;
    bf16x8 x0 = *(bf16x8*)(p + base);
    bf16x8 x1 = *(bf16x8*)(p + base + 64);
    bf16x8 o0, o1;
#pragma unroll
    for (int j = 0; j < 8; ++j) {
        float inv = __expf(-(float)(i0 + j) * 0.14391156831212787f);
        float ang = (float)s * inv;
        float sn, c;
        __sincosf(ang, &sn, &c);
        sn *= sc; c *= sc;
        float a = (float)x0[j], bb = (float)x1[j];
        o0[j] = (bf16_t)(a * c - bb * sn);
        o1[j] = (bf16_t)(bb * c + a * sn);
    }
    *(bf16x8*)(p + base) = o0;
    *(bf16x8*)(p + base + 64) = o1;
}

// ---------------- fused QKV GEMM: [q|k|v] = x @ W^T; V written transposed ----------------
// grid (48, 32): seg = bx/16 (0=q,1=k,2=v), 256 thr, m97 structure.
__global__ __launch_bounds__(256) void gemm_qkv(const bf16_t* __restrict__ A,
                                                const bf16_t* __restrict__ Wq,
                                                const bf16_t* __restrict__ Wk,
                                                const bf16_t* __restrict__ Wv,
                                                bf16_t* __restrict__ qb,
                                                bf16_t* __restrict__ kb,
                                                bf16_t* __restrict__ vtb) {
    __shared__ __align__(16) bf16_t As[128 * 32];
    __shared__ __align__(16) bf16_t Bs[128 * 32];
    const int K = D_;
    int t = threadIdx.x;
    int w = t >> 6, lane = t & 63, lo = lane & 15, hi = lane >> 4;
    int seg = blockIdx.x >> 4;
    int n0 = (blockIdx.x & 15) * 128;
    int m0 = blockIdx.y * 128;
    const bf16_t* Bt = (seg == 0) ? Wq : (seg == 1) ? Wk : Wv;
    int wm = (w & 1) * 64, wn = (w >> 1) * 64;
    f32x4 acc[4][4] = {};
    const bf16_t* ga = A + (size_t)(m0 + (t >> 2)) * K + (t & 3) * 8;
    const bf16_t* gb = Bt + (size_t)(n0 + (t >> 2)) * K + (t & 3) * 8;
    for (int k0 = 0; k0 < K; k0 += 32) {
        async16(ga + k0,                  As + t * 8);
        async16(ga + (size_t)64 * K + k0, As + 2048 + t * 8);
        async16(gb + k0,                  Bs + t * 8);
        async16(gb + (size_t)64 * K + k0, Bs + 2048 + t * 8);
        __syncthreads();
        bf16x8 af[4], bfr[4];
#pragma unroll
        for (int ms = 0; ms < 4; ++ms)
            af[ms] = *(const bf16x8*)(As + (wm + ms * 16 + lo) * 32 + hi * 8);
#pragma unroll
        for (int ns = 0; ns < 4; ++ns)
            bfr[ns] = *(const bf16x8*)(Bs + (wn + ns * 16 + lo) * 32 + hi * 8);
#pragma unroll
        for (int ms = 0; ms < 4; ++ms)
#pragma unroll
            for (int ns = 0; ns < 4; ++ns)
                acc[ms][ns] = __builtin_amdgcn_mfma_f32_16x16x32_bf16(af[ms], bfr[ns], acc[ms][ns], 0, 0, 0);
        __syncthreads();
    }
    if (seg < 2) {
        bf16_t* C = (seg == 0) ? qb : kb;
#pragma unroll
        for (int ms = 0; ms < 4; ++ms)
#pragma unroll
            for (int ns = 0; ns < 4; ++ns)
#pragma unroll
                for (int r = 0; r < 4; ++r)
                    C[(size_t)(m0 + wm + ms * 16 + hi * 4 + r) * D_ + n0 + wn + ns * 16 + lo] = (bf16_t)acc[ms][ns][r];
    } else {
        // V transposed: vtb[b][d][s], d = col, s = row % S
#pragma unroll
        for (int ms = 0; ms < 4; ++ms) {
            int mrow = m0 + wm + ms * 16 + hi * 4;
            int bb = mrow >> 11, s = mrow & (S_ - 1);
#pragma unroll
            for (int ns = 0; ns < 4; ++ns) {
                int d = n0 + wn + ns * 16 + lo;
                bf16x4 pv = { (bf16_t)acc[ms][ns][0], (bf16_t)acc[ms][ns][1],
                              (bf16_t)acc[ms][ns][2], (bf16_t)acc[ms][ns][3] };
                *(bf16x4*)(vtb + (size_t)bb * D_ * S_ + (size_t)d * S_ + s) = pv;
            }
        }
    }
}

// ---------------- GEMM: C[M,N] = A[M,K] * Bt[N,K]^T, fp32 out (final proj) ----------------
__global__ __launch_bounds__(256) void gemm_bt_f32(const bf16_t* __restrict__ A,
                                                   const bf16_t* __restrict__ Bt,
                                                   float* __restrict__ C,
                                                   int M, int N, int K) {
    __shared__ __align__(16) bf16_t As[128 * 32];
    __shared__ __align__(16) bf16_t Bs[128 * 32];
    int t = threadIdx.x;
    int w = t >> 6, lane = t & 63, lo = lane & 15, hi = lane >> 4;
    int m0 = blockIdx.y * 128, n0 = blockIdx.x * 128;
    int wm = (w & 1) * 64, wn = (w >> 1) * 64;
    f32x4 acc[4][4] = {};
    const bf16_t* ga = A + (size_t)(m0 + (t >> 2)) * K + (t & 3) * 8;
    const bf16_t* gb = Bt + (size_t)(n0 + (t >> 2)) * K + (t & 3) * 8;
    for (int k0 = 0; k0 < K; k0 += 32) {
        async16(ga + k0,                  As + t * 8);
        async16(ga + (size_t)64 * K + k0, As + 2048 + t * 8);
        async16(gb + k0,                  Bs + t * 8);
        async16(gb + (size_t)64 * K + k0, Bs + 2048 + t * 8);
        __syncthreads();
        bf16x8 af[4], bfr[4];
#pragma unroll
        for (int ms = 0; ms < 4; ++ms)
            af[ms] = *(const bf16x8*)(As + (wm + ms * 16 + lo) * 32 + hi * 8);
#pragma unroll
        for (int ns = 0; ns < 4; ++ns)
            bfr[ns] = *(const bf16x8*)(Bs + (wn + ns * 16 + lo) * 32 + hi * 8);
#pragma unroll
        for (int ms = 0; ms < 4; ++ms)
#pragma unroll
            for (int ns = 0; ns < 4; ++ns)
                acc[ms][ns] = __builtin_amdgcn_mfma_f32_16x16x32_bf16(af[ms], bfr[ns], acc[ms][ns], 0, 0, 0);
        __syncthreads();
    }
#pragma unroll
    for (int ms = 0; ms < 4; ++ms)
#pragma unroll
        for (int ns = 0; ns < 4; ++ns)
#pragma unroll
            for (int r = 0; r < 4; ++r)
                C[(size_t)(m0 + wm + ms * 16 + hi * 4 + r) * N + n0 + wn + ns * 16 + lo] = acc[ms][ns][r];
}

// ---------------- Flash attention v3: S^T trick, no-max softmax, P in-register ----------------
// grid (16, 32), 256 thr = 4 waves. Block does q-subtiles bx and 31-bx (64 rows each)
// -> exactly 33 k-tile units per block (perfect balance).
__global__ __launch_bounds__(256) void attn_kernel(const bf16_t* __restrict__ q,
                                                   const bf16_t* __restrict__ k,
                                                   const bf16_t* __restrict__ vt,
                                                   bf16_t* __restrict__ o) {
    __shared__ __align__(16) bf16_t Ks[64 * 128];   // [krow][d], chunk16 swz ^ (row&15)
    __shared__ __align__(16) bf16_t Vs[128 * 64];   // [d][kk],   chunk8  swz ^ (d&7)
    int t = threadIdx.x;
    int w = t >> 6, lane = t & 63, lo = lane & 15, hi = lane >> 4;
    int bx = blockIdx.x;
    int b = blockIdx.y >> 4, h = blockIdx.y & 15;
    const size_t head_off = (size_t)b * S_ * D_ + (size_t)h * HD_;
    const size_t vhead_off = ((size_t)b * D_ + (size_t)h * HD_) * S_;

#pragma unroll 1
    for (int pass = 0; pass < 2; ++pass) {
        int qt = pass ? (31 - bx) : bx;   // 64-row q-subtile index
        int q0 = qt * 64;
        int qg = q0 + w * 16 + lo;        // this lane's q row (lane dim = q!)
        // Q fragments (already scaled by 1/sqrt(HD) in rope)
        bf16x8 aq[4];
#pragma unroll
        for (int c = 0; c < 4; ++c)
            aq[c] = *(const bf16x8*)(q + head_off + (size_t)qg * D_ + c * 32 + hi * 8);

        float l_part = 0.f;
        f32x4 oacc[8] = {};
        int nkt = qt + 1;
        for (int kt = 0; kt < nkt; ++kt) {
            int k0 = kt * 64;
            __syncthreads();  // prior compute's LDS reads done
            // stage K tile (64x128): 16 chunks of 1KB, wave w does 4
#pragma unroll
            for (int i = 0; i < 4; ++i) {
                int chunk = w * 4 + i;
                int r = chunk * 4 + (lane >> 4);
                int lc = (lane & 15) ^ (r & 15);
                async16(k + head_off + (size_t)(k0 + r) * D_ + lc * 8,
                        Ks + chunk * 512 + lane * 8);
            }
            // stage V^T tile (128 d x 64 kk)
#pragma unroll
            for (int i = 0; i < 4; ++i) {
                int chunk = w * 4 + i;
                int d = chunk * 8 + (lane >> 3);
                int lc = (lane & 7) ^ (d & 7);
                async16(vt + vhead_off + (size_t)d * S_ + k0 + lc * 8,
                        Vs + chunk * 512 + lane * 8);
            }
            __syncthreads();  // staging visible

            // S^T = K * Q^T : C cols = q (lo), C rows = k (hi*4+r)
            f32x4 sacc[4] = {};
#pragma unroll
            for (int c = 0; c < 4; ++c) {
#pragma unroll
                for (int nt = 0; nt < 4; ++nt) {
                    int row = nt * 16 + lo;
                    int pc = (c * 4 + hi) ^ lo;
                    bf16x8 ak = *(const bf16x8*)(Ks + row * 128 + pc * 8);
                    sacc[nt] = __builtin_amdgcn_mfma_f32_16x16x32_bf16(ak, aq[c], sacc[nt], 0, 0, 0);
                }
            }
            // exp (no max subtraction), mask on diagonal tile, accumulate l,
            // P^T stays in registers as the 16x16x16 B-fragment.
            bool diag = (kt == qt);
            bf16x4 pf[4];
#pragma unroll
            for (int nt = 0; nt < 4; ++nt) {
#pragma unroll
                for (int r = 0; r < 4; ++r) {
                    float e = __expf(fminf(sacc[nt][r], 60.f));
                    if (diag) {
                        int kg = k0 + nt * 16 + hi * 4 + r;
                        if (kg > qg) e = 0.f;
                    }
                    l_part += e;
                    pf[nt][r] = (bf16_t)e;
                }
            }
            // O^T[d][q] += V^T * P^T  (16x16x16: A k = hi*4+j, B k = hi*4+j)
#pragma unroll
            for (int nt = 0; nt < 4; ++nt) {
                int kkb = nt * 16 + hi * 4;
                int chunk8 = kkb >> 3, rem = kkb & 7;
#pragma unroll
                for (int dt = 0; dt < 8; ++dt) {
                    int d = dt * 16 + lo;
                    bf16x4 av = *(const bf16x4*)(Vs + d * 64 + (chunk8 ^ (d & 7)) * 8 + rem);
                    oacc[dt] = mfma16x16x16_bf16(av, pf[nt], oacc[dt]);
                }
            }
        }
        // epilogue: reduce l over hi-groups (q = lo is lane-resident), write O^T
        float l = l_part;
        l += __shfl_xor(l, 16);
        l += __shfl_xor(l, 32);
        float rl = 1.0f / l;
#pragma unroll
        for (int dt = 0; dt < 8; ++dt) {
            bf16x4 ov = { (bf16_t)(oacc[dt][0] * rl), (bf16_t)(oacc[dt][1] * rl),
                          (bf16_t)(oacc[dt][2] * rl), (bf16_t)(oacc[dt][3] * rl) };
            *(bf16x4*)(o + head_off + (size_t)qg * D_ + dt * 16 + hi * 4) = ov;
        }
    }
}

// ---------------- launch ----------------
extern "C" void kernel_launch(void* const* d_in, const int* in_sizes, int n_in,
                              void* d_out, int out_size, void* d_ws, size_t ws_size,
                              hipStream_t stream) {
    (void)in_sizes; (void)n_in; (void)out_size; (void)ws_size;
    const float* x  = (const float*)d_in[0];
    const float* Wq = (const float*)d_in[1];
    const float* Wk = (const float*)d_in[2];
    const float* Wv = (const float*)d_in[3];
    const float* Wo = (const float*)d_in[4];
    char* ws = (char*)d_ws;
    bf16_t* xb  = (bf16_t*)(ws);
    bf16_t* Wqb = (bf16_t*)(ws + 16777216);
    bf16_t* Wkb = (bf16_t*)(ws + 25165824);
    bf16_t* Wvb = (bf16_t*)(ws + 33554432);
    bf16_t* Wob = (bf16_t*)(ws + 41943040);
    bf16_t* qb  = (bf16_t*)(ws + 50331648);
    bf16_t* kb  = (bf16_t*)(ws + 67108864);
    bf16_t* vtb = (bf16_t*)(ws + 83886080);
    bf16_t* ob  = (bf16_t*)(ws + 100663296);
    float* out = (float*)d_out;

    f2b_multi<<<dim3(4096, 6), 256, 0, stream>>>(x, Wq, Wk, Wv, Wo, xb, Wqb, Wkb, Wvb, Wob);

    gemm_qkv<<<dim3(48, 32), 256, 0, stream>>>(xb, Wqb, Wkb, Wvb, qb, kb, vtb);

    rope_kernel<<<dim3((B_ * S_ * H_ * 8) / 256, 2), 256, 0, stream>>>(qb, kb);

    attn_kernel<<<dim3(16, B_ * H_), 256, 0, stream>>>(qb, kb, vtb, ob);

    gemm_bt_f32<<<dim3(D_ / 128, (B_ * S_) / 128), 256, 0, stream>>>(ob, Wob, out, B_ * S_, D_, D_);
}